// Round 6
// baseline (234.013 us; speedup 1.0000x reference)
//
#include <hip/hip_runtime.h>
#include <stdint.h>

// ---------------------------------------------------------------------------
// Problem constants (from reference)
// ---------------------------------------------------------------------------
#define C_RMIN 100000.0f
#define C_RMAX 10000000.0f
#define C_CMIN 1e-07f
#define C_CMAX 1e-04f
#define C_DT   0.1f
#define C_EPS  0.05f
#define C_COUP 0.2f

typedef __attribute__((ext_vector_type(8))) short bf16x8;
typedef __attribute__((ext_vector_type(4))) float floatx4;

// ---------------------------------------------------------------------------
// Threefry-2x32 (exact JAX semantics). Host+device.
// ---------------------------------------------------------------------------
__host__ __device__ inline void tf2x32(uint32_t k0, uint32_t k1,
                                       uint32_t& x0, uint32_t& x1) {
  uint32_t ks2 = k0 ^ k1 ^ 0x1BD11BDAu;
  uint32_t a = x0 + k0, b = x1 + k1;
#define TFR(r) a += b; b = (b << (r)) | (b >> (32 - (r))); b ^= a;
  TFR(13) TFR(15) TFR(26) TFR(6)
  a += k1;  b += ks2 + 1u;
  TFR(17) TFR(29) TFR(16) TFR(24)
  a += ks2; b += k0 + 2u;
  TFR(13) TFR(15) TFR(26) TFR(6)
  a += k0;  b += k1 + 3u;
  TFR(17) TFR(29) TFR(16) TFR(24)
  a += k1;  b += ks2 + 4u;
  TFR(13) TFR(15) TFR(26) TFR(6)
  a += ks2; b += k0 + 5u;
#undef TFR
  x0 = a; x1 = b;
}

// jax.random.uniform element e, PARTITIONABLE threefry (jax>=0.5 default):
// one block per element, counter = (0, e), bits = out0 ^ out1.
__device__ inline float unif01(uint32_t k0, uint32_t k1, uint32_t e) {
  uint32_t x0 = 0u, x1 = e;
  tf2x32(k0, k1, x0, x1);
  uint32_t bits = x0 ^ x1;
  return __uint_as_float((bits >> 9) | 0x3F800000u) - 1.0f;
}

__device__ inline float theta_eff(float t) {
  t = fminf(fmaxf(t, -10.0f), 10.0f);
  return (fabsf(t) < 0.01f) ? 0.0f : t;
}

__device__ inline float sigmoidf(float x) { return 1.0f / (1.0f + expf(-x)); }

__device__ inline float noise_mul(float u) { return (u * 2.0f - 1.0f) * C_EPS + 1.0f; }

// ---------------------------------------------------------------------------
// PREP0 (fused, heavy-work-first):
//   bids [0,32)   -> denom2 partials + zero cnt[128]
//   bids [32,36)  -> S1eff
//   bids [36,548) -> beta12 interleaved (both cascades per thread, 8 t's)
// ---------------------------------------------------------------------------
__global__ __launch_bounds__(256) void prep0_kernel(
    const float* __restrict__ Rlf, const float* __restrict__ Clf,
    const float* __restrict__ theta1, const float* __restrict__ theta2,
    float* __restrict__ beta12, float* __restrict__ S1eff,
    float* __restrict__ denom2p, int* __restrict__ cnt,
    uint32_t k1a, uint32_t k1b, uint32_t k4a, uint32_t k4b,
    uint32_t kR1a, uint32_t kR1b, uint32_t kC1a, uint32_t kC1b,
    uint32_t kM1a, uint32_t kM1b,
    uint32_t kR2a, uint32_t kR2b, uint32_t kC2a, uint32_t kC2b,
    uint32_t kM2a, uint32_t kM2b) {
  int bid = blockIdx.x;
  if (bid < 32) {
    if (threadIdx.x < 4) cnt[bid * 4 + threadIdx.x] = 0;   // zero combine counters
    int n = bid >> 3, p = bid & 7;
    int o = threadIdx.x & 31;
    int jc = threadIdx.x >> 5;          // 0..7
    int j0 = p * 8 + jc;                // 0..63
    float part = 0.0f;
    for (int j = j0; j < 1058; j += 64) {
      float t = theta_eff(theta2[j * 32 + o]);
      float u = unif01(k4a, k4b, (uint32_t)((n * 1058 + j) * 32 + o));
      part += fabsf(t * noise_mul(u));
    }
    __shared__ float red[256];
    red[jc * 32 + o] = part;
    __syncthreads();
    if (jc == 0) {
      float s = 0.0f;
      for (int q = 0; q < 8; ++q) s += red[q * 32 + o];
      denom2p[(n * 8 + p) * 32 + o] = s;
    }
  } else if (bid < 36) {
    int n = bid - 32;
    int o = threadIdx.x;
    if (o < 32) {
      float tn[34];
      float den = 0.0f;
      for (int m = 0; m < 34; ++m) {
        float t = theta_eff(theta1[m * 32 + o]);
        float u = unif01(k1a, k1b, (uint32_t)((n * 34 + m) * 32 + o));
        float v = t * noise_mul(u);
        tn[m] = v;
        den += fabsf(v);
      }
      den += 1e-10f;
      for (int m = 0; m < 33; ++m)
        S1eff[(n * 33 + m) * 32 + o] = tn[m] / den;
    }
  } else {
    // beta12: thread handles 8 t's for fixed (n,k), BOTH cascades interleaved.
    int u = (bid - 36) * 256 + threadIdx.x;   // [0, 131072)
    int k = u & 1023;
    int tc = (u >> 10) & 31;
    int n = u >> 15;                           // 0..3
    float Rt1 = sigmoidf(Rlf[k * 2 + 0]) * (C_RMAX - C_RMIN) + C_RMIN;
    float Ct1 = sigmoidf(Clf[k * 2 + 0]) * (C_CMAX - C_CMIN) + C_CMIN;
    float Rt2 = sigmoidf(Rlf[k * 2 + 1]) * (C_RMAX - C_RMIN) + C_RMIN;
    float Ct2 = sigmoidf(Clf[k * 2 + 1]) * (C_CMAX - C_CMIN) + C_CMIN;
#pragma unroll
    for (int it = 0; it < 8; ++it) {
      int t = tc * 8 + it;
      uint32_t e = (uint32_t)((t * 1024 + k) * 4 + n);
      float nR1 = noise_mul(unif01(kR1a, kR1b, e));
      float nC1 = noise_mul(unif01(kC1a, kC1b, e));
      float mu1 = unif01(kM1a, kM1b, e) * C_COUP + 1.0f;
      float rc1 = mu1 * (Rt1 * nR1) * (Ct1 * nC1);
      float nR2 = noise_mul(unif01(kR2a, kR2b, e));
      float nC2 = noise_mul(unif01(kC2a, kC2b, e));
      float mu2 = unif01(kM2a, kM2b, e) * C_COUP + 1.0f;
      float rc2 = mu2 * (Rt2 * nR2) * (Ct2 * nC2);
      float2 bb = { rc1 / (rc1 + C_DT), rc2 / (rc2 + C_DT) };
      *(float2*)&beta12[(size_t)(((n * 256 + t) * 1024) + k) * 2] = bb;
    }
  }
}

// ---------------------------------------------------------------------------
// PREP1 (fused, heavy-first): bids [0,128) -> a1 (first pmac);
//                             bids [128,657) -> S2eff (sums denom partials).
// ---------------------------------------------------------------------------
__global__ __launch_bounds__(256) void prep1_kernel(
    const float* __restrict__ theta2, const float* __restrict__ denom2p,
    float* __restrict__ S2eff,
    const float* __restrict__ x, const float* __restrict__ S1eff,
    float* __restrict__ a1, uint32_t k4a, uint32_t k4b) {
  int bid = blockIdx.x;
  __shared__ float xs[32][256];
  if (bid < 128) {
    int n = bid >> 5, b = bid & 31;
    int t = threadIdx.x;
    const float* xp = x + (size_t)((n * 32 + b) * 32) * 256;
    for (int m = 0; m < 32; ++m) xs[m][t] = xp[m * 256 + t];
    __syncthreads();
    const float* S = S1eff + n * 33 * 32;
    float* ap = a1 + (size_t)((n * 32 + b) * 32) * 256;
    for (int o = 0; o < 32; ++o) {
      float z = S[32 * 32 + o];
#pragma unroll
      for (int m = 0; m < 32; ++m) z += xs[m][t] * S[m * 32 + o];
      ap[o * 256 + t] = 0.05f + 0.5f * tanhf((z - 0.3f) * 3.0f);
    }
  } else {
    int idx = (bid - 128) * 256 + threadIdx.x;
    if (idx >= 4 * 1057 * 32) return;
    int o = idx & 31;
    int r = idx >> 5;
    int j = r % 1057;
    int n = r / 1057;
    float den = 1e-10f;
#pragma unroll
    for (int p = 0; p < 8; ++p) den += denom2p[(n * 8 + p) * 32 + o];
    float t = theta_eff(theta2[j * 32 + o]);
    float u = unif01(k4a, k4b, (uint32_t)((n * 1058 + j) * 32 + o));
    S2eff[idx] = t * noise_mul(u) / den;
  }
}

// ---------------------------------------------------------------------------
// FK4: producer/consumer MFMA fused filter cascade + partial pmac2 +
//      last-block combine (absorbs cb).
// Grid: 512 blocks = (nb)*4 + qr; 320 threads.
//   tid 0..255  : producers, filter k = qr*256 + tid
//   tid 256..319: consumer wave (MFMA), y planes pre-split hi/lo bf16 in
//                 fragment-ready order -> zero repack VALU.
// After the loop: atomicAdd(cnt[nb]); the 4th block combines quarters +
// direct channels + bias + tanh and writes out[nb].
// ---------------------------------------------------------------------------
#define YP 264                      // uint16 per t-row (256 + 8 pad)
#define YPLANE (16 * YP)            // one chunk plane (uint16 count)

__global__ __launch_bounds__(320) void fk4_kernel(
    const float* __restrict__ a1, const float* __restrict__ S2eff,
    const float* __restrict__ beta12, float* __restrict__ zpart,
    float* __restrict__ out, int* __restrict__ cnt,
    uint32_t k01a, uint32_t k01b, uint32_t k02a, uint32_t k02b) {
  int bid = blockIdx.x;
  int qr = bid & 3;
  int nb = bid >> 2;
  int n = nb >> 5, b = nb & 31;
  int tid = threadIdx.x;

  __shared__ __align__(16) uint8_t smem[50176];
  uint16_t* yh = (uint16_t*)smem;                    // 2 bufs * YPLANE = 16896 B
  uint16_t* yl = (uint16_t*)(smem + 16896);          // 16896 B
  short*    wf = (short*)(smem + 33792);             // 16*512*2 = 16384 B
  __shared__ int sflag;

  const float* S2n = S2eff + (size_t)n * 1057 * 32;
  const float* a1nb = a1 + (size_t)nb * 8192;
  const float* bp = beta12 + ((size_t)n * 262144 + qr * 256) * 2;
  float* zout = zpart + (size_t)bid * 8192;

  float s1 = 0.0f, s2 = 0.0f;
  int cc = 0;

  if (tid < 256) {
    int k = qr * 256 + tid;
    uint32_t e0 = (uint32_t)((k * 4 + n) * 32 + b);
    s1 = unif01(k01a, k01b, e0);
    s2 = unif01(k02a, k02b, e0);
    cc = k >> 5;
    // build W bf16 B-fragments in LDS
    for (int it = 0; it < 32; ++it) {
      int widx = it * 256 + tid;            // [0, 8192)
      int j = widx & 7;
      int lane_ = (widx >> 3) & 63;
      int ot = (widx >> 9) & 1;
      int ks = widx >> 10;                  // 0..7
      int sub = ((lane_ >> 4) << 3) + j;    // k within 32-chunk
      int jrow = (qr * 8 + ks) * 33 + 1 + sub;
      float w = S2n[jrow * 32 + ot * 16 + (lane_ & 15)];
      uint32_t wb = __float_as_uint(w);
      uint32_t hi = (wb + 0x7FFFu + ((wb >> 16) & 1u)) >> 16;   // RNE bf16
      wf[(ks * 2 + ot) * 512 + lane_ * 8 + j] = (short)(uint16_t)hi;
    }
  }
  __syncthreads();

  for (int c = 0; c <= 16; ++c) {
    if (tid < 256) {
      if (c < 16) {
        uint16_t* yhb = yh + (c & 1) * YPLANE;
        uint16_t* ylb = yl + (c & 1) * YPLANE;
        int t0 = c * 16;
#pragma unroll
        for (int it = 0; it < 16; ++it) {
          int t = t0 + it;
          uint32_t sb = __float_as_uint(s2);
          uint32_t hi = sb >> 16;
          float fhi = __uint_as_float(sb & 0xFFFF0000u);
          uint32_t lo = __float_as_uint(s2 - fhi) >> 16;   // exact split
          yhb[it * YP + tid] = (uint16_t)hi;
          ylb[it * YP + tid] = (uint16_t)lo;
          float2 bb = *(const float2*)&bp[(size_t)(t * 1024 + tid) * 2];
          float xv = a1nb[cc * 256 + t];
          s2 = bb.y * s2 + (1.0f - bb.y) * s1;   // cascade 2 eats pre-update s1
          s1 = bb.x * s1 + (1.0f - bb.x) * xv;
        }
      }
    } else if (c >= 1) {
      int lane = tid - 256;
      int tc = lane & 15, q = lane >> 4;
      const uint16_t* yhr = yh + ((c - 1) & 1) * YPLANE + tc * YP + q * 8;
      const uint16_t* ylr = yl + ((c - 1) & 1) * YPLANE + tc * YP + q * 8;
      floatx4 acc0a = {0,0,0,0}, acc0b = {0,0,0,0};
      floatx4 acc1a = {0,0,0,0}, acc1b = {0,0,0,0};
#pragma unroll
      for (int ks = 0; ks < 8; ++ks) {
        bf16x8 ah = *(const bf16x8*)(yhr + ks * 32);
        bf16x8 al = *(const bf16x8*)(ylr + ks * 32);
        bf16x8 bh0 = *(const bf16x8*)&wf[(ks * 2 + 0) * 512 + lane * 8];
        bf16x8 bh1 = *(const bf16x8*)&wf[(ks * 2 + 1) * 512 + lane * 8];
        if (ks & 1) {
          acc0b = __builtin_amdgcn_mfma_f32_16x16x32_bf16(ah, bh0, acc0b, 0, 0, 0);
          acc0b = __builtin_amdgcn_mfma_f32_16x16x32_bf16(al, bh0, acc0b, 0, 0, 0);
          acc1b = __builtin_amdgcn_mfma_f32_16x16x32_bf16(ah, bh1, acc1b, 0, 0, 0);
          acc1b = __builtin_amdgcn_mfma_f32_16x16x32_bf16(al, bh1, acc1b, 0, 0, 0);
        } else {
          acc0a = __builtin_amdgcn_mfma_f32_16x16x32_bf16(ah, bh0, acc0a, 0, 0, 0);
          acc0a = __builtin_amdgcn_mfma_f32_16x16x32_bf16(al, bh0, acc0a, 0, 0, 0);
          acc1a = __builtin_amdgcn_mfma_f32_16x16x32_bf16(ah, bh1, acc1a, 0, 0, 0);
          acc1a = __builtin_amdgcn_mfma_f32_16x16x32_bf16(al, bh1, acc1a, 0, 0, 0);
        }
      }
      int t0 = (c - 1) * 16;
      floatx4 r0 = acc0a + acc0b;
      floatx4 r1 = acc1a + acc1b;
      // D layout: col = lane&15 (=o within tile), row = q*4 + reg (=t_local)
      *(floatx4*)&zout[tc * 256 + t0 + q * 4] = r0;
      *(floatx4*)&zout[(16 + tc) * 256 + t0 + q * 4] = r1;
    }
    __syncthreads();
  }

  // ---- last-of-4 combine (absorbs cb_kernel) ----
  // __syncthreads above drained all waves' vmcnt; fence publishes this XCD's
  // L2 before the device-scope atomic establishes happens-before.
  if (tid == 0) {
    __threadfence();
    sflag = (atomicAdd(&cnt[nb], 1) == 3) ? 1 : 0;
  }
  __syncthreads();
  if (sflag == 0) return;
  __threadfence();   // acquire: invalidate local caches before reading peers

  float* xs = (float*)smem;   // reuse LDS: [32][256] = 32 KB <= 50176
  if (tid < 256) {
    for (int c2 = 0; c2 < 32; ++c2) xs[c2 * 256 + tid] = a1nb[c2 * 256 + tid];
  }
  __syncthreads();
  if (tid < 256) {
    int t = tid;
    const float* zp = zpart + (size_t)nb * 4 * 8192;
    float* op = out + (size_t)nb * 8192;
    for (int o = 0; o < 32; ++o) {
      float z = S2n[1056 * 32 + o];
#pragma unroll
      for (int c2 = 0; c2 < 32; ++c2) z += xs[c2 * 256 + t] * S2n[(c2 * 33) * 32 + o];
      z += zp[o * 256 + t] + zp[8192 + o * 256 + t] +
           zp[16384 + o * 256 + t] + zp[24576 + o * 256 + t];
      op[o * 256 + t] = 0.05f + 0.5f * tanhf((z - 0.3f) * 3.0f);
    }
  }
}

// ---------------------------------------------------------------------------
// Launch
// ---------------------------------------------------------------------------
struct KeyPair { uint32_t a, b; };

// jax.random.split(key, 4), PARTITIONABLE (foldlike): key_i = threefry(key,(0,i))
static inline void split4_host(KeyPair key, KeyPair out[4]) {
  for (uint32_t i = 0; i < 4; ++i) {
    uint32_t x0 = 0u, x1 = i;
    tf2x32(key.a, key.b, x0, x1);
    out[i] = {x0, x1};
  }
}

extern "C" void kernel_launch(void* const* d_in, const int* in_sizes, int n_in,
                              void* d_out, int out_size, void* d_ws, size_t ws_size,
                              hipStream_t stream) {
  const float* x   = (const float*)d_in[0];   // (4,32,32,256)
  const float* th1 = (const float*)d_in[1];   // (34,32)
  const float* th2 = (const float*)d_in[2];   // (1058,32)
  const float* Rlf = (const float*)d_in[3];   // (32,32,2)
  const float* Clf = (const float*)d_in[4];   // (32,32,2)
  float* out = (float*)d_out;                 // (4,32,32,256)
  float* ws = (float*)d_ws;

  // workspace layout (floats)
  float* S1     = ws;                  // 4224
  float* den2p  = ws + 4224;           // 1024
  float* S2     = ws + 5248;           // 135296
  float* a1     = ws + 140544;         // 1048576
  float* beta12 = ws + 1189120;        // 2097152 (interleaved b1,b2)
  float* zpart  = ws + 3286272;        // 4194304 (512 blocks x 8192)
  int*   cnt    = (int*)(ws + 7480576);// 128 ints (~29.9 MB total)

  KeyPair root{0u, 42u};
  KeyPair kk[4];  split4_host(root, kk);     // {k1, k2, k3, k4}
  KeyPair f1[4];  split4_host(kk[1], f1);    // {kR1, kC1, kmu1, k01}
  KeyPair f2[4];  split4_host(kk[2], f2);    // {kR2, kC2, kmu2, k02}

  prep0_kernel<<<dim3(548), dim3(256), 0, stream>>>(
      Rlf, Clf, th1, th2, beta12, S1, den2p, cnt,
      kk[0].a, kk[0].b, kk[3].a, kk[3].b,
      f1[0].a, f1[0].b, f1[1].a, f1[1].b, f1[2].a, f1[2].b,
      f2[0].a, f2[0].b, f2[1].a, f2[1].b, f2[2].a, f2[2].b);
  prep1_kernel<<<dim3(657), dim3(256), 0, stream>>>(
      th2, den2p, S2, x, S1, a1, kk[3].a, kk[3].b);
  fk4_kernel<<<dim3(512), dim3(320), 0, stream>>>(
      a1, S2, beta12, zpart, out, cnt, f1[3].a, f1[3].b, f2[3].a, f2[3].b);
}

// Round 7
// 158.723 us; speedup vs baseline: 1.4743x; 1.4743x over previous
//
#include <hip/hip_runtime.h>
#include <stdint.h>

// ---------------------------------------------------------------------------
// Problem constants (from reference)
// ---------------------------------------------------------------------------
#define C_RMIN 100000.0f
#define C_RMAX 10000000.0f
#define C_CMIN 1e-07f
#define C_CMAX 1e-04f
#define C_DT   0.1f
#define C_EPS  0.05f
#define C_COUP 0.2f

typedef __attribute__((ext_vector_type(8))) short bf16x8;
typedef __attribute__((ext_vector_type(4))) float floatx4;

// ---------------------------------------------------------------------------
// Threefry-2x32 (exact JAX semantics). Host+device.
// ---------------------------------------------------------------------------
__host__ __device__ inline void tf2x32(uint32_t k0, uint32_t k1,
                                       uint32_t& x0, uint32_t& x1) {
  uint32_t ks2 = k0 ^ k1 ^ 0x1BD11BDAu;
  uint32_t a = x0 + k0, b = x1 + k1;
#define TFR(r) a += b; b = (b << (r)) | (b >> (32 - (r))); b ^= a;
  TFR(13) TFR(15) TFR(26) TFR(6)
  a += k1;  b += ks2 + 1u;
  TFR(17) TFR(29) TFR(16) TFR(24)
  a += ks2; b += k0 + 2u;
  TFR(13) TFR(15) TFR(26) TFR(6)
  a += k0;  b += k1 + 3u;
  TFR(17) TFR(29) TFR(16) TFR(24)
  a += k1;  b += ks2 + 4u;
  TFR(13) TFR(15) TFR(26) TFR(6)
  a += ks2; b += k0 + 5u;
#undef TFR
  x0 = a; x1 = b;
}

// jax.random.uniform element e, PARTITIONABLE threefry (jax>=0.5 default):
// one block per element, counter = (0, e), bits = out0 ^ out1.
__device__ inline float unif01(uint32_t k0, uint32_t k1, uint32_t e) {
  uint32_t x0 = 0u, x1 = e;
  tf2x32(k0, k1, x0, x1);
  uint32_t bits = x0 ^ x1;
  return __uint_as_float((bits >> 9) | 0x3F800000u) - 1.0f;
}

__device__ inline float theta_eff(float t) {
  t = fminf(fmaxf(t, -10.0f), 10.0f);
  return (fabsf(t) < 0.01f) ? 0.0f : t;
}

__device__ inline float sigmoidf(float x) { return 1.0f / (1.0f + expf(-x)); }

__device__ inline float noise_mul(float u) { return (u * 2.0f - 1.0f) * C_EPS + 1.0f; }

// ---------------------------------------------------------------------------
// PREP0 (fused, heavy-work-first):
//   bids [0,32)   -> denom2 partials
//   bids [32,36)  -> S1eff
//   bids [36,548) -> beta12 interleaved (both cascades per thread, 8 t's)
// ---------------------------------------------------------------------------
__global__ __launch_bounds__(256) void prep0_kernel(
    const float* __restrict__ Rlf, const float* __restrict__ Clf,
    const float* __restrict__ theta1, const float* __restrict__ theta2,
    float* __restrict__ beta12, float* __restrict__ S1eff,
    float* __restrict__ denom2p,
    uint32_t k1a, uint32_t k1b, uint32_t k4a, uint32_t k4b,
    uint32_t kR1a, uint32_t kR1b, uint32_t kC1a, uint32_t kC1b,
    uint32_t kM1a, uint32_t kM1b,
    uint32_t kR2a, uint32_t kR2b, uint32_t kC2a, uint32_t kC2b,
    uint32_t kM2a, uint32_t kM2b) {
  int bid = blockIdx.x;
  if (bid < 32) {
    int n = bid >> 3, p = bid & 7;
    int o = threadIdx.x & 31;
    int jc = threadIdx.x >> 5;          // 0..7
    int j0 = p * 8 + jc;                // 0..63
    float part = 0.0f;
    for (int j = j0; j < 1058; j += 64) {
      float t = theta_eff(theta2[j * 32 + o]);
      float u = unif01(k4a, k4b, (uint32_t)((n * 1058 + j) * 32 + o));
      part += fabsf(t * noise_mul(u));
    }
    __shared__ float red[256];
    red[jc * 32 + o] = part;
    __syncthreads();
    if (jc == 0) {
      float s = 0.0f;
      for (int q = 0; q < 8; ++q) s += red[q * 32 + o];
      denom2p[(n * 8 + p) * 32 + o] = s;
    }
  } else if (bid < 36) {
    int n = bid - 32;
    int o = threadIdx.x;
    if (o < 32) {
      float tn[34];
      float den = 0.0f;
      for (int m = 0; m < 34; ++m) {
        float t = theta_eff(theta1[m * 32 + o]);
        float u = unif01(k1a, k1b, (uint32_t)((n * 34 + m) * 32 + o));
        float v = t * noise_mul(u);
        tn[m] = v;
        den += fabsf(v);
      }
      den += 1e-10f;
      for (int m = 0; m < 33; ++m)
        S1eff[(n * 33 + m) * 32 + o] = tn[m] / den;
    }
  } else {
    // beta12: thread handles 8 t's for fixed (n,k), BOTH cascades interleaved.
    int u = (bid - 36) * 256 + threadIdx.x;   // [0, 131072)
    int k = u & 1023;
    int tc = (u >> 10) & 31;
    int n = u >> 15;                           // 0..3
    float Rt1 = sigmoidf(Rlf[k * 2 + 0]) * (C_RMAX - C_RMIN) + C_RMIN;
    float Ct1 = sigmoidf(Clf[k * 2 + 0]) * (C_CMAX - C_CMIN) + C_CMIN;
    float Rt2 = sigmoidf(Rlf[k * 2 + 1]) * (C_RMAX - C_RMIN) + C_RMIN;
    float Ct2 = sigmoidf(Clf[k * 2 + 1]) * (C_CMAX - C_CMIN) + C_CMIN;
#pragma unroll
    for (int it = 0; it < 8; ++it) {
      int t = tc * 8 + it;
      uint32_t e = (uint32_t)((t * 1024 + k) * 4 + n);
      float nR1 = noise_mul(unif01(kR1a, kR1b, e));
      float nC1 = noise_mul(unif01(kC1a, kC1b, e));
      float mu1 = unif01(kM1a, kM1b, e) * C_COUP + 1.0f;
      float rc1 = mu1 * (Rt1 * nR1) * (Ct1 * nC1);
      float nR2 = noise_mul(unif01(kR2a, kR2b, e));
      float nC2 = noise_mul(unif01(kC2a, kC2b, e));
      float mu2 = unif01(kM2a, kM2b, e) * C_COUP + 1.0f;
      float rc2 = mu2 * (Rt2 * nR2) * (Ct2 * nC2);
      float2 bb = { rc1 / (rc1 + C_DT), rc2 / (rc2 + C_DT) };
      *(float2*)&beta12[(size_t)(((n * 256 + t) * 1024) + k) * 2] = bb;
    }
  }
}

// ---------------------------------------------------------------------------
// PREP1 (fused, heavy-first): bids [0,128) -> a1 (first pmac);
//                             bids [128,657) -> S2eff (sums denom partials).
// ---------------------------------------------------------------------------
__global__ __launch_bounds__(256) void prep1_kernel(
    const float* __restrict__ theta2, const float* __restrict__ denom2p,
    float* __restrict__ S2eff,
    const float* __restrict__ x, const float* __restrict__ S1eff,
    float* __restrict__ a1, uint32_t k4a, uint32_t k4b) {
  int bid = blockIdx.x;
  __shared__ float xs[32][256];
  if (bid < 128) {
    int n = bid >> 5, b = bid & 31;
    int t = threadIdx.x;
    const float* xp = x + (size_t)((n * 32 + b) * 32) * 256;
    for (int m = 0; m < 32; ++m) xs[m][t] = xp[m * 256 + t];
    __syncthreads();
    const float* S = S1eff + n * 33 * 32;
    float* ap = a1 + (size_t)((n * 32 + b) * 32) * 256;
    for (int o = 0; o < 32; ++o) {
      float z = S[32 * 32 + o];
#pragma unroll
      for (int m = 0; m < 32; ++m) z += xs[m][t] * S[m * 32 + o];
      ap[o * 256 + t] = 0.05f + 0.5f * tanhf((z - 0.3f) * 3.0f);
    }
  } else {
    int idx = (bid - 128) * 256 + threadIdx.x;
    if (idx >= 4 * 1057 * 32) return;
    int o = idx & 31;
    int r = idx >> 5;
    int j = r % 1057;
    int n = r / 1057;
    float den = 1e-10f;
#pragma unroll
    for (int p = 0; p < 8; ++p) den += denom2p[(n * 8 + p) * 32 + o];
    float t = theta_eff(theta2[j * 32 + o]);
    float u = unif01(k4a, k4b, (uint32_t)((n * 1058 + j) * 32 + o));
    S2eff[idx] = t * noise_mul(u) / den;
  }
}

// ---------------------------------------------------------------------------
// FK5: producer/consumer MFMA fused filter cascade + partial pmac2.
// (R6's zero-repack hi/lo bf16 planes, WITHOUT the cross-block combine —
//  device-scope fences forced per-block L2 writebacks and cost ~100 µs.)
// Grid: 512 blocks = nb*4 + qr; 320 threads.
//   tid 0..255  : producers, filter k = qr*256 + tid
//   tid 256..319: consumer wave (MFMA), y planes pre-split hi/lo bf16 in
//                 fragment-ready order -> zero repack VALU.
// ---------------------------------------------------------------------------
#define YP 264                      // uint16 per t-row (256 + 8 pad)
#define YPLANE (16 * YP)            // one chunk plane (uint16 count)

__global__ __launch_bounds__(320) void fk5_kernel(
    const float* __restrict__ a1, const float* __restrict__ S2eff,
    const float* __restrict__ beta12, float* __restrict__ zpart,
    uint32_t k01a, uint32_t k01b, uint32_t k02a, uint32_t k02b) {
  int bid = blockIdx.x;
  int qr = bid & 3;
  int nb = bid >> 2;
  int n = nb >> 5, b = nb & 31;
  int tid = threadIdx.x;

  __shared__ __align__(16) uint8_t smem[50176];
  uint16_t* yh = (uint16_t*)smem;                    // 2 bufs * YPLANE = 16896 B
  uint16_t* yl = (uint16_t*)(smem + 16896);          // 16896 B
  short*    wf = (short*)(smem + 33792);             // 16*512*2 = 16384 B

  const float* S2n = S2eff + (size_t)n * 1057 * 32;
  const float* a1nb = a1 + (size_t)nb * 8192;
  const float* bp = beta12 + ((size_t)n * 262144 + qr * 256) * 2;
  float* zout = zpart + (size_t)bid * 8192;

  float s1 = 0.0f, s2 = 0.0f;
  int cc = 0;

  if (tid < 256) {
    int k = qr * 256 + tid;
    uint32_t e0 = (uint32_t)((k * 4 + n) * 32 + b);
    s1 = unif01(k01a, k01b, e0);
    s2 = unif01(k02a, k02b, e0);
    cc = k >> 5;
    // build W bf16 B-fragments in LDS
    for (int it = 0; it < 32; ++it) {
      int widx = it * 256 + tid;            // [0, 8192)
      int j = widx & 7;
      int lane_ = (widx >> 3) & 63;
      int ot = (widx >> 9) & 1;
      int ks = widx >> 10;                  // 0..7
      int sub = ((lane_ >> 4) << 3) + j;    // k within 32-chunk
      int jrow = (qr * 8 + ks) * 33 + 1 + sub;
      float w = S2n[jrow * 32 + ot * 16 + (lane_ & 15)];
      uint32_t wb = __float_as_uint(w);
      uint32_t hi = (wb + 0x7FFFu + ((wb >> 16) & 1u)) >> 16;   // RNE bf16
      wf[(ks * 2 + ot) * 512 + lane_ * 8 + j] = (short)(uint16_t)hi;
    }
  }
  __syncthreads();

  for (int c = 0; c <= 16; ++c) {
    if (tid < 256) {
      if (c < 16) {
        uint16_t* yhb = yh + (c & 1) * YPLANE;
        uint16_t* ylb = yl + (c & 1) * YPLANE;
        int t0 = c * 16;
#pragma unroll
        for (int it = 0; it < 16; ++it) {
          int t = t0 + it;
          uint32_t sb = __float_as_uint(s2);
          uint32_t hi = sb >> 16;
          float fhi = __uint_as_float(sb & 0xFFFF0000u);
          uint32_t lo = __float_as_uint(s2 - fhi) >> 16;   // exact split
          yhb[it * YP + tid] = (uint16_t)hi;
          ylb[it * YP + tid] = (uint16_t)lo;
          float2 bb = *(const float2*)&bp[(size_t)(t * 1024 + tid) * 2];
          float xv = a1nb[cc * 256 + t];
          s2 = bb.y * s2 + (1.0f - bb.y) * s1;   // cascade 2 eats pre-update s1
          s1 = bb.x * s1 + (1.0f - bb.x) * xv;
        }
      }
    } else if (c >= 1) {
      int lane = tid - 256;
      int tc = lane & 15, q = lane >> 4;
      const uint16_t* yhr = yh + ((c - 1) & 1) * YPLANE + tc * YP + q * 8;
      const uint16_t* ylr = yl + ((c - 1) & 1) * YPLANE + tc * YP + q * 8;
      floatx4 acc0a = {0,0,0,0}, acc0b = {0,0,0,0};
      floatx4 acc1a = {0,0,0,0}, acc1b = {0,0,0,0};
#pragma unroll
      for (int ks = 0; ks < 8; ++ks) {
        bf16x8 ah = *(const bf16x8*)(yhr + ks * 32);
        bf16x8 al = *(const bf16x8*)(ylr + ks * 32);
        bf16x8 bh0 = *(const bf16x8*)&wf[(ks * 2 + 0) * 512 + lane * 8];
        bf16x8 bh1 = *(const bf16x8*)&wf[(ks * 2 + 1) * 512 + lane * 8];
        if (ks & 1) {
          acc0b = __builtin_amdgcn_mfma_f32_16x16x32_bf16(ah, bh0, acc0b, 0, 0, 0);
          acc0b = __builtin_amdgcn_mfma_f32_16x16x32_bf16(al, bh0, acc0b, 0, 0, 0);
          acc1b = __builtin_amdgcn_mfma_f32_16x16x32_bf16(ah, bh1, acc1b, 0, 0, 0);
          acc1b = __builtin_amdgcn_mfma_f32_16x16x32_bf16(al, bh1, acc1b, 0, 0, 0);
        } else {
          acc0a = __builtin_amdgcn_mfma_f32_16x16x32_bf16(ah, bh0, acc0a, 0, 0, 0);
          acc0a = __builtin_amdgcn_mfma_f32_16x16x32_bf16(al, bh0, acc0a, 0, 0, 0);
          acc1a = __builtin_amdgcn_mfma_f32_16x16x32_bf16(ah, bh1, acc1a, 0, 0, 0);
          acc1a = __builtin_amdgcn_mfma_f32_16x16x32_bf16(al, bh1, acc1a, 0, 0, 0);
        }
      }
      int t0 = (c - 1) * 16;
      floatx4 r0 = acc0a + acc0b;
      floatx4 r1 = acc1a + acc1b;
      // D layout: col = lane&15 (=o within tile), row = q*4 + reg (=t_local)
      *(floatx4*)&zout[tc * 256 + t0 + q * 4] = r0;
      *(floatx4*)&zout[(16 + tc) * 256 + t0 + q * 4] = r1;
    }
    __syncthreads();
  }
}

// ---------------------------------------------------------------------------
// CB: combine 4 K-quarters + direct-channel term + bias + activation.
// Separate kernel: plain launch-edge dependency — no device-scope fences
// (G16: per-block __threadfence on CDNA4 = L2 writeback, ~100 µs total; R6).
// ---------------------------------------------------------------------------
__global__ __launch_bounds__(256) void cb_kernel(
    const float* __restrict__ a1, const float* __restrict__ S2eff,
    const float* __restrict__ zpart, float* __restrict__ out) {
  int nb = blockIdx.x;
  int n = nb >> 5;
  int t = threadIdx.x;
  __shared__ float xs[32][256];
  const float* a1nb = a1 + (size_t)nb * 8192;
  for (int c = 0; c < 32; ++c) xs[c][t] = a1nb[c * 256 + t];
  __syncthreads();
  const float* S2n = S2eff + (size_t)n * 1057 * 32;
  const float* zp = zpart + (size_t)nb * 4 * 8192;
  float* op = out + (size_t)nb * 8192;
  for (int o = 0; o < 32; ++o) {
    float z = S2n[1056 * 32 + o];
#pragma unroll
    for (int c = 0; c < 32; ++c) z += xs[c][t] * S2n[(c * 33) * 32 + o];
    z += zp[o * 256 + t] + zp[8192 + o * 256 + t] +
         zp[16384 + o * 256 + t] + zp[24576 + o * 256 + t];
    op[o * 256 + t] = 0.05f + 0.5f * tanhf((z - 0.3f) * 3.0f);
  }
}

// ---------------------------------------------------------------------------
// Launch
// ---------------------------------------------------------------------------
struct KeyPair { uint32_t a, b; };

// jax.random.split(key, 4), PARTITIONABLE (foldlike): key_i = threefry(key,(0,i))
static inline void split4_host(KeyPair key, KeyPair out[4]) {
  for (uint32_t i = 0; i < 4; ++i) {
    uint32_t x0 = 0u, x1 = i;
    tf2x32(key.a, key.b, x0, x1);
    out[i] = {x0, x1};
  }
}

extern "C" void kernel_launch(void* const* d_in, const int* in_sizes, int n_in,
                              void* d_out, int out_size, void* d_ws, size_t ws_size,
                              hipStream_t stream) {
  const float* x   = (const float*)d_in[0];   // (4,32,32,256)
  const float* th1 = (const float*)d_in[1];   // (34,32)
  const float* th2 = (const float*)d_in[2];   // (1058,32)
  const float* Rlf = (const float*)d_in[3];   // (32,32,2)
  const float* Clf = (const float*)d_in[4];   // (32,32,2)
  float* out = (float*)d_out;                 // (4,32,32,256)
  float* ws = (float*)d_ws;

  // workspace layout (floats)
  float* S1     = ws;                  // 4224
  float* den2p  = ws + 4224;           // 1024
  float* S2     = ws + 5248;           // 135296
  float* a1     = ws + 140544;         // 1048576
  float* beta12 = ws + 1189120;        // 2097152 (interleaved b1,b2)
  float* zpart  = ws + 3286272;        // 4194304 (512 blocks x 8192) ~29.9 MB

  KeyPair root{0u, 42u};
  KeyPair kk[4];  split4_host(root, kk);     // {k1, k2, k3, k4}
  KeyPair f1[4];  split4_host(kk[1], f1);    // {kR1, kC1, kmu1, k01}
  KeyPair f2[4];  split4_host(kk[2], f2);    // {kR2, kC2, kmu2, k02}

  prep0_kernel<<<dim3(548), dim3(256), 0, stream>>>(
      Rlf, Clf, th1, th2, beta12, S1, den2p,
      kk[0].a, kk[0].b, kk[3].a, kk[3].b,
      f1[0].a, f1[0].b, f1[1].a, f1[1].b, f1[2].a, f1[2].b,
      f2[0].a, f2[0].b, f2[1].a, f2[1].b, f2[2].a, f2[2].b);
  prep1_kernel<<<dim3(657), dim3(256), 0, stream>>>(
      th2, den2p, S2, x, S1, a1, kk[3].a, kk[3].b);
  fk5_kernel<<<dim3(512), dim3(320), 0, stream>>>(
      a1, S2, beta12, zpart, f1[3].a, f1[3].b, f2[3].a, f2[3].b);
  cb_kernel<<<dim3(128), dim3(256), 0, stream>>>(a1, S2, zpart, out);
}

// Round 8
// 142.764 us; speedup vs baseline: 1.6392x; 1.1118x over previous
//
#include <hip/hip_runtime.h>
#include <stdint.h>

// ---------------------------------------------------------------------------
// Problem constants (from reference)
// ---------------------------------------------------------------------------
#define C_RMIN 100000.0f
#define C_RMAX 10000000.0f
#define C_CMIN 1e-07f
#define C_CMAX 1e-04f
#define C_DT   0.1f
#define C_EPS  0.05f
#define C_COUP 0.2f

typedef __attribute__((ext_vector_type(8))) short bf16x8;
typedef __attribute__((ext_vector_type(4))) float floatx4;

// ---------------------------------------------------------------------------
// Threefry-2x32 (exact JAX semantics). Host+device.
// ---------------------------------------------------------------------------
__host__ __device__ inline void tf2x32(uint32_t k0, uint32_t k1,
                                       uint32_t& x0, uint32_t& x1) {
  uint32_t ks2 = k0 ^ k1 ^ 0x1BD11BDAu;
  uint32_t a = x0 + k0, b = x1 + k1;
#define TFR(r) a += b; b = (b << (r)) | (b >> (32 - (r))); b ^= a;
  TFR(13) TFR(15) TFR(26) TFR(6)
  a += k1;  b += ks2 + 1u;
  TFR(17) TFR(29) TFR(16) TFR(24)
  a += ks2; b += k0 + 2u;
  TFR(13) TFR(15) TFR(26) TFR(6)
  a += k0;  b += k1 + 3u;
  TFR(17) TFR(29) TFR(16) TFR(24)
  a += k1;  b += ks2 + 4u;
  TFR(13) TFR(15) TFR(26) TFR(6)
  a += ks2; b += k0 + 5u;
#undef TFR
  x0 = a; x1 = b;
}

// jax.random.uniform element e, PARTITIONABLE threefry (jax>=0.5 default):
// one block per element, counter = (0, e), bits = out0 ^ out1.
__device__ inline float unif01(uint32_t k0, uint32_t k1, uint32_t e) {
  uint32_t x0 = 0u, x1 = e;
  tf2x32(k0, k1, x0, x1);
  uint32_t bits = x0 ^ x1;
  return __uint_as_float((bits >> 9) | 0x3F800000u) - 1.0f;
}

__device__ inline float theta_eff(float t) {
  t = fminf(fmaxf(t, -10.0f), 10.0f);
  return (fabsf(t) < 0.01f) ? 0.0f : t;
}

__device__ inline float sigmoidf(float x) { return 1.0f / (1.0f + expf(-x)); }

__device__ inline float noise_mul(float u) { return (u * 2.0f - 1.0f) * C_EPS + 1.0f; }

// ---------------------------------------------------------------------------
// PREP (single prep kernel, heavy-work-first):
//   bids [0,32)    -> denom2 partials (64-way j split)
//   bids [32,160)  -> a1 (first pmac) with S1eff regenerated in-block
//   bids [160,672) -> beta12 interleaved (both cascades per thread, 8 t's)
// S2eff is NOT materialized — fk6/cb2 regenerate their weights in-block.
// ---------------------------------------------------------------------------
__global__ __launch_bounds__(256) void prep_kernel(
    const float* __restrict__ Rlf, const float* __restrict__ Clf,
    const float* __restrict__ theta1, const float* __restrict__ theta2,
    const float* __restrict__ x,
    float* __restrict__ beta12, float* __restrict__ a1,
    float* __restrict__ denom2p,
    uint32_t k1a, uint32_t k1b, uint32_t k4a, uint32_t k4b,
    uint32_t kR1a, uint32_t kR1b, uint32_t kC1a, uint32_t kC1b,
    uint32_t kM1a, uint32_t kM1b,
    uint32_t kR2a, uint32_t kR2b, uint32_t kC2a, uint32_t kC2b,
    uint32_t kM2a, uint32_t kM2b) {
  __shared__ float red[256];
  __shared__ float vsm[34 * 32];
  __shared__ float S1s[33 * 32];
  __shared__ float xs[32][256];
  int bid = blockIdx.x;
  int tid = threadIdx.x;
  if (bid < 32) {
    // ---- denom2 partials: denom2p[(n*8+p)*32+o] ----
    int n = bid >> 3, p = bid & 7;
    int o = tid & 31;
    int jc = tid >> 5;                  // 0..7
    int j0 = p * 8 + jc;                // 0..63
    float part = 0.0f;
    for (int j = j0; j < 1058; j += 64) {
      float t = theta_eff(theta2[j * 32 + o]);
      float u = unif01(k4a, k4b, (uint32_t)((n * 1058 + j) * 32 + o));
      part += fabsf(t * noise_mul(u));
    }
    red[jc * 32 + o] = part;
    __syncthreads();
    if (jc == 0) {
      float s = 0.0f;
      for (int q = 0; q < 8; ++q) s += red[q * 32 + o];
      denom2p[(n * 8 + p) * 32 + o] = s;
    }
  } else if (bid < 160) {
    // ---- a1[n][b][o][t], S1eff regenerated in-block ----
    int blk = bid - 32;
    int n = blk >> 5, b = blk & 31;
    int o = tid & 31, mq = tid >> 5;    // mq 0..7
    float dp = 0.0f;
    for (int m = mq; m < 34; m += 8) {
      float t = theta_eff(theta1[m * 32 + o]);
      float v = t * noise_mul(unif01(k1a, k1b, (uint32_t)((n * 34 + m) * 32 + o)));
      vsm[m * 32 + o] = v;
      dp += fabsf(v);
    }
    red[mq * 32 + o] = dp;
    // stage x while RNG settles
    const float* xp = x + (size_t)((n * 32 + b) * 32) * 256;
    __syncthreads();
    for (int idx = tid; idx < 33 * 32; idx += 256) {
      int oo = idx & 31;
      float den = 1e-10f;
#pragma unroll
      for (int q = 0; q < 8; ++q) den += red[q * 32 + oo];
      S1s[idx] = vsm[idx] / den;
    }
    for (int m = 0; m < 32; ++m) xs[m][tid] = xp[m * 256 + tid];
    __syncthreads();
    float* ap = a1 + (size_t)((n * 32 + b) * 32) * 256;
    int t = tid;
    for (int oo = 0; oo < 32; ++oo) {
      float z = S1s[32 * 32 + oo];
#pragma unroll
      for (int m = 0; m < 32; ++m) z += xs[m][t] * S1s[m * 32 + oo];
      ap[oo * 256 + t] = 0.05f + 0.5f * tanhf((z - 0.3f) * 3.0f);
    }
  } else {
    // ---- beta12: thread handles 8 t's for fixed (n,k), both cascades ----
    int u = (bid - 160) * 256 + tid;    // [0, 131072)
    int k = u & 1023;
    int tc = (u >> 10) & 31;
    int n = u >> 15;                    // 0..3
    float Rt1 = sigmoidf(Rlf[k * 2 + 0]) * (C_RMAX - C_RMIN) + C_RMIN;
    float Ct1 = sigmoidf(Clf[k * 2 + 0]) * (C_CMAX - C_CMIN) + C_CMIN;
    float Rt2 = sigmoidf(Rlf[k * 2 + 1]) * (C_RMAX - C_RMIN) + C_RMIN;
    float Ct2 = sigmoidf(Clf[k * 2 + 1]) * (C_CMAX - C_CMIN) + C_CMIN;
#pragma unroll
    for (int it = 0; it < 8; ++it) {
      int t = tc * 8 + it;
      uint32_t e = (uint32_t)((t * 1024 + k) * 4 + n);
      float nR1 = noise_mul(unif01(kR1a, kR1b, e));
      float nC1 = noise_mul(unif01(kC1a, kC1b, e));
      float mu1 = unif01(kM1a, kM1b, e) * C_COUP + 1.0f;
      float rc1 = mu1 * (Rt1 * nR1) * (Ct1 * nC1);
      float nR2 = noise_mul(unif01(kR2a, kR2b, e));
      float nC2 = noise_mul(unif01(kC2a, kC2b, e));
      float mu2 = unif01(kM2a, kM2b, e) * C_COUP + 1.0f;
      float rc2 = mu2 * (Rt2 * nR2) * (Ct2 * nC2);
      float2 bb = { rc1 / (rc1 + C_DT), rc2 / (rc2 + C_DT) };
      *(float2*)&beta12[(size_t)(((n * 256 + t) * 1024) + k) * 2] = bb;
    }
  }
}

// ---------------------------------------------------------------------------
// FK6: producer/consumer MFMA fused filter cascade + partial pmac2.
// W regenerated in-block from theta2 + denom2p (no S2eff pass).
// Grid: 512 blocks = nb*4 + qr; 320 threads.
//   tid 0..255  : producers, filter k = qr*256 + tid
//   tid 256..319: consumer wave (MFMA), zero-repack hi/lo bf16 planes.
// No cross-block combine: device-scope fences cost ~100 µs on CDNA4 (R6).
// ---------------------------------------------------------------------------
#define YP 264                      // uint16 per t-row (256 + 8 pad)
#define YPLANE (16 * YP)            // one chunk plane (uint16 count)

__global__ __launch_bounds__(320) void fk6_kernel(
    const float* __restrict__ a1, const float* __restrict__ theta2,
    const float* __restrict__ denom2p,
    const float* __restrict__ beta12, float* __restrict__ zpart,
    uint32_t k01a, uint32_t k01b, uint32_t k02a, uint32_t k02b,
    uint32_t k4a, uint32_t k4b) {
  int bid = blockIdx.x;
  int qr = bid & 3;
  int nb = bid >> 2;
  int n = nb >> 5, b = nb & 31;
  int tid = threadIdx.x;

  __shared__ __align__(16) uint8_t smem[50176];
  uint16_t* yh = (uint16_t*)smem;                    // 2 bufs * YPLANE = 16896 B
  uint16_t* yl = (uint16_t*)(smem + 16896);          // 16896 B
  short*    wf = (short*)(smem + 33792);             // 16*512*2 = 16384 B
  __shared__ float sden[32];

  const float* a1nb = a1 + (size_t)nb * 8192;
  const float* bp = beta12 + ((size_t)n * 262144 + qr * 256) * 2;
  float* zout = zpart + (size_t)bid * 8192;

  if (tid < 32) {
    float d = 1e-10f;
#pragma unroll
    for (int q = 0; q < 8; ++q) d += denom2p[(n * 8 + q) * 32 + tid];
    sden[tid] = d;
  }
  __syncthreads();

  float s1 = 0.0f, s2 = 0.0f;
  int cc = 0;

  if (tid < 256) {
    int k = qr * 256 + tid;
    uint32_t e0 = (uint32_t)((k * 4 + n) * 32 + b);
    s1 = unif01(k01a, k01b, e0);
    s2 = unif01(k02a, k02b, e0);
    cc = k >> 5;
    // build W bf16 B-fragments in LDS, regenerating weights from theta2
    for (int it = 0; it < 32; ++it) {
      int widx = it * 256 + tid;            // [0, 8192)
      int j = widx & 7;
      int lane_ = (widx >> 3) & 63;
      int ot = (widx >> 9) & 1;
      int ks = widx >> 10;                  // 0..7
      int sub = ((lane_ >> 4) << 3) + j;    // k within 32-chunk
      int jrow = (qr * 8 + ks) * 33 + 1 + sub;
      int oo = ot * 16 + (lane_ & 15);
      float th = theta_eff(theta2[jrow * 32 + oo]);
      float u = unif01(k4a, k4b, (uint32_t)((n * 1058 + jrow) * 32 + oo));
      float w = th * noise_mul(u) / sden[oo];
      uint32_t wb = __float_as_uint(w);
      uint32_t hi = (wb + 0x7FFFu + ((wb >> 16) & 1u)) >> 16;   // RNE bf16
      wf[(ks * 2 + ot) * 512 + lane_ * 8 + j] = (short)(uint16_t)hi;
    }
  }
  __syncthreads();

  for (int c = 0; c <= 16; ++c) {
    if (tid < 256) {
      if (c < 16) {
        uint16_t* yhb = yh + (c & 1) * YPLANE;
        uint16_t* ylb = yl + (c & 1) * YPLANE;
        int t0 = c * 16;
#pragma unroll
        for (int it = 0; it < 16; ++it) {
          int t = t0 + it;
          uint32_t sb = __float_as_uint(s2);
          uint32_t hi = sb >> 16;
          float fhi = __uint_as_float(sb & 0xFFFF0000u);
          uint32_t lo = __float_as_uint(s2 - fhi) >> 16;   // exact split
          yhb[it * YP + tid] = (uint16_t)hi;
          ylb[it * YP + tid] = (uint16_t)lo;
          float2 bb = *(const float2*)&bp[(size_t)(t * 1024 + tid) * 2];
          float xv = a1nb[cc * 256 + t];
          s2 = bb.y * s2 + (1.0f - bb.y) * s1;   // cascade 2 eats pre-update s1
          s1 = bb.x * s1 + (1.0f - bb.x) * xv;
        }
      }
    } else if (c >= 1) {
      int lane = tid - 256;
      int tc = lane & 15, q = lane >> 4;
      const uint16_t* yhr = yh + ((c - 1) & 1) * YPLANE + tc * YP + q * 8;
      const uint16_t* ylr = yl + ((c - 1) & 1) * YPLANE + tc * YP + q * 8;
      floatx4 acc0a = {0,0,0,0}, acc0b = {0,0,0,0};
      floatx4 acc1a = {0,0,0,0}, acc1b = {0,0,0,0};
#pragma unroll
      for (int ks = 0; ks < 8; ++ks) {
        bf16x8 ah = *(const bf16x8*)(yhr + ks * 32);
        bf16x8 al = *(const bf16x8*)(ylr + ks * 32);
        bf16x8 bh0 = *(const bf16x8*)&wf[(ks * 2 + 0) * 512 + lane * 8];
        bf16x8 bh1 = *(const bf16x8*)&wf[(ks * 2 + 1) * 512 + lane * 8];
        if (ks & 1) {
          acc0b = __builtin_amdgcn_mfma_f32_16x16x32_bf16(ah, bh0, acc0b, 0, 0, 0);
          acc0b = __builtin_amdgcn_mfma_f32_16x16x32_bf16(al, bh0, acc0b, 0, 0, 0);
          acc1b = __builtin_amdgcn_mfma_f32_16x16x32_bf16(ah, bh1, acc1b, 0, 0, 0);
          acc1b = __builtin_amdgcn_mfma_f32_16x16x32_bf16(al, bh1, acc1b, 0, 0, 0);
        } else {
          acc0a = __builtin_amdgcn_mfma_f32_16x16x32_bf16(ah, bh0, acc0a, 0, 0, 0);
          acc0a = __builtin_amdgcn_mfma_f32_16x16x32_bf16(al, bh0, acc0a, 0, 0, 0);
          acc1a = __builtin_amdgcn_mfma_f32_16x16x32_bf16(ah, bh1, acc1a, 0, 0, 0);
          acc1a = __builtin_amdgcn_mfma_f32_16x16x32_bf16(al, bh1, acc1a, 0, 0, 0);
        }
      }
      int t0 = (c - 1) * 16;
      floatx4 r0 = acc0a + acc0b;
      floatx4 r1 = acc1a + acc1b;
      // D layout: col = lane&15 (=o within tile), row = q*4 + reg (=t_local)
      *(floatx4*)&zout[tc * 256 + t0 + q * 4] = r0;
      *(floatx4*)&zout[(16 + tc) * 256 + t0 + q * 4] = r1;
    }
    __syncthreads();
  }
}

// ---------------------------------------------------------------------------
// CB2: combine 4 K-quarters + direct-channel term + bias + activation.
// Direct/bias weights regenerated in-block (no S2eff). Separate kernel:
// plain launch-edge dependency — no device-scope fences (R6 lesson).
// ---------------------------------------------------------------------------
__global__ __launch_bounds__(256) void cb2_kernel(
    const float* __restrict__ a1, const float* __restrict__ theta2,
    const float* __restrict__ denom2p,
    const float* __restrict__ zpart, float* __restrict__ out,
    uint32_t k4a, uint32_t k4b) {
  int nb = blockIdx.x;
  int n = nb >> 5;
  int t = threadIdx.x;
  __shared__ float xs[32][256];
  __shared__ float wd[33 * 32];   // r<32: direct channel c=r (j=r*33); r=32: bias (j=1056)
  __shared__ float sden[32];
  if (t < 32) {
    float d = 1e-10f;
#pragma unroll
    for (int q = 0; q < 8; ++q) d += denom2p[(n * 8 + q) * 32 + t];
    sden[t] = d;
  }
  const float* a1nb = a1 + (size_t)nb * 8192;
  for (int c = 0; c < 32; ++c) xs[c][t] = a1nb[c * 256 + t];
  __syncthreads();
  for (int idx = t; idx < 33 * 32; idx += 256) {
    int r = idx >> 5, oo = idx & 31;
    int j = (r < 32) ? r * 33 : 1056;
    float th = theta_eff(theta2[j * 32 + oo]);
    float u = unif01(k4a, k4b, (uint32_t)((n * 1058 + j) * 32 + oo));
    wd[idx] = th * noise_mul(u) / sden[oo];
  }
  __syncthreads();
  const float* zp = zpart + (size_t)nb * 4 * 8192;
  float* op = out + (size_t)nb * 8192;
  for (int o = 0; o < 32; ++o) {
    float z = wd[32 * 32 + o];
#pragma unroll
    for (int c = 0; c < 32; ++c) z += xs[c][t] * wd[c * 32 + o];
    z += zp[o * 256 + t] + zp[8192 + o * 256 + t] +
         zp[16384 + o * 256 + t] + zp[24576 + o * 256 + t];
    op[o * 256 + t] = 0.05f + 0.5f * tanhf((z - 0.3f) * 3.0f);
  }
}

// ---------------------------------------------------------------------------
// Launch
// ---------------------------------------------------------------------------
struct KeyPair { uint32_t a, b; };

// jax.random.split(key, 4), PARTITIONABLE (foldlike): key_i = threefry(key,(0,i))
static inline void split4_host(KeyPair key, KeyPair out[4]) {
  for (uint32_t i = 0; i < 4; ++i) {
    uint32_t x0 = 0u, x1 = i;
    tf2x32(key.a, key.b, x0, x1);
    out[i] = {x0, x1};
  }
}

extern "C" void kernel_launch(void* const* d_in, const int* in_sizes, int n_in,
                              void* d_out, int out_size, void* d_ws, size_t ws_size,
                              hipStream_t stream) {
  const float* x   = (const float*)d_in[0];   // (4,32,32,256)
  const float* th1 = (const float*)d_in[1];   // (34,32)
  const float* th2 = (const float*)d_in[2];   // (1058,32)
  const float* Rlf = (const float*)d_in[3];   // (32,32,2)
  const float* Clf = (const float*)d_in[4];   // (32,32,2)
  float* out = (float*)d_out;                 // (4,32,32,256)
  float* ws = (float*)d_ws;

  // workspace layout (floats)
  float* den2p  = ws;                  // 1024
  float* a1     = ws + 1024;           // 1048576
  float* beta12 = ws + 1049600;        // 2097152 (interleaved b1,b2)
  float* zpart  = ws + 3146752;        // 4194304 (512 blocks x 8192) ~28 MB

  KeyPair root{0u, 42u};
  KeyPair kk[4];  split4_host(root, kk);     // {k1, k2, k3, k4}
  KeyPair f1[4];  split4_host(kk[1], f1);    // {kR1, kC1, kmu1, k01}
  KeyPair f2[4];  split4_host(kk[2], f2);    // {kR2, kC2, kmu2, k02}

  prep_kernel<<<dim3(672), dim3(256), 0, stream>>>(
      Rlf, Clf, th1, th2, x, beta12, a1, den2p,
      kk[0].a, kk[0].b, kk[3].a, kk[3].b,
      f1[0].a, f1[0].b, f1[1].a, f1[1].b, f1[2].a, f1[2].b,
      f2[0].a, f2[0].b, f2[1].a, f2[1].b, f2[2].a, f2[2].b);
  fk6_kernel<<<dim3(512), dim3(320), 0, stream>>>(
      a1, th2, den2p, beta12, zpart,
      f1[3].a, f1[3].b, f2[3].a, f2[3].b, kk[3].a, kk[3].b);
  cb2_kernel<<<dim3(128), dim3(256), 0, stream>>>(
      a1, th2, den2p, zpart, out, kk[3].a, kk[3].b);
}